// Round 1
// baseline (164.102 us; speedup 1.0000x reference)
//
#include <hip/hip_runtime.h>

#define NBATCH 16
#define CIN_ 128
#define COUT_ 128
#define H_ 128
#define W_ 128
#define TH 8   // output rows per workgroup in conv kernel

typedef short bf16x8 __attribute__((ext_vector_type(8)));
typedef float f32x4 __attribute__((ext_vector_type(4)));
typedef unsigned short u16x8 __attribute__((ext_vector_type(8)));

__device__ __forceinline__ unsigned short f32_to_bf16(float f) {
  unsigned int u = __float_as_uint(f);
  u += 0x7fffu + ((u >> 16) & 1u);   // round-to-nearest-even
  return (unsigned short)(u >> 16);
}

// ---------------- kernel 1: decode block mask -> active lists ----------------
// lists[0..3]  = cnt per output block
// lists[4+ob*4+s] = input block index of slot s
__global__ void make_lists_k(const float* __restrict__ mask, int* __restrict__ lists) {
  if (threadIdx.x == 0) {
    for (int i = 0; i < 20; ++i) lists[i] = 0;
    for (int ob = 0; ob < 4; ++ob) {
      int c = 0;
      for (int ib = 0; ib < 4; ++ib) {
        // mask[co][ci][0][0], co=ob*32, ci=ib*32 ; constant within a block
        float v = mask[(size_t)((ob * 32) * CIN_ + ib * 32) * 9];
        if (v != 0.0f) { lists[4 + ob * 4 + c] = ib; ++c; }
      }
      lists[ob] = c;
    }
  }
}

// ---------------- kernel 2: pack masked weights to bf16, MFMA A-layout -------
// wpack[ob][slot][khkw][co(32)][ci(32)]  (ci contiguous)
__global__ __launch_bounds__(256) void pack_w_k(const float* __restrict__ weight,
                                                const float* __restrict__ mask,
                                                const int* __restrict__ lists,
                                                unsigned short* __restrict__ wpack) {
  const int khkw = blockIdx.x;   // 0..8
  const int slot = blockIdx.y;   // 0..3
  const int ob   = blockIdx.z;   // 0..3
  if (slot >= lists[ob]) return;
  const int ib = lists[4 + ob * 4 + slot];
  const int kh = khkw / 3, kw = khkw % 3;
  for (int e = threadIdx.x; e < 1024; e += 256) {
    const int co = e >> 5, ci = e & 31;
    const int cog = ob * 32 + co, cig = ib * 32 + ci;
    const size_t widx = ((size_t)(cog * CIN_ + cig) * 3 + kh) * 3 + kw;
    const float v = weight[widx] * mask[widx];
    wpack[(size_t)((ob * 4 + slot) * 9 + khkw) * 1024 + e] = f32_to_bf16(v);
  }
}

// ---------------- kernel 3: transpose+convert x: NCHW f32 -> [b][h][w][ci] bf16
__global__ __launch_bounds__(256) void transpose_cvt_k(const float* __restrict__ x,
                                                       unsigned short* __restrict__ xt) {
  __shared__ float lds[128 * 65];     // [ci][w], pitch 65 to break bank conflicts
  const int tid = threadIdx.x;
  const int w0 = blockIdx.x * 64;     // 0 or 64
  const int h  = blockIdx.y;
  const int b  = blockIdx.z;

  // load: coalesced rows of x (w contiguous)
  {
    const int wl = tid & 63;          // w within tile
    const int c0 = tid >> 6;          // 0..3
    for (int ci = c0; ci < 128; ci += 4) {
      lds[ci * 65 + wl] = x[((size_t)(b * CIN_ + ci) * H_ + h) * W_ + w0 + wl];
    }
  }
  __syncthreads();

  // store: each thread emits one 16B chunk (8 ci) per rep; fully coalesced
  {
    const int chunk = tid & 15;       // which 8-ci chunk of the pixel
    const int wloc  = tid >> 4;       // 0..15
    for (int rep = 0; rep < 4; ++rep) {
      const int w = wloc + rep * 16;  // 0..63
      u16x8 v;
#pragma unroll
      for (int j = 0; j < 8; ++j) {
        v[j] = f32_to_bf16(lds[(chunk * 8 + j) * 65 + w]);
      }
      *(u16x8*)(xt + ((size_t)(b * H_ + h) * W_ + (w0 + w)) * CIN_ + chunk * 8) = v;
    }
  }
}

// ---------------- kernel 4: block-sparse implicit-GEMM conv via MFMA ---------
// grid: (H/TH, B, 4 output blocks), block 256 (4 waves)
// WG computes out[b][ob*32..+31][h0..h0+TH-1][0..127]
__global__ __launch_bounds__(256) void conv_mfma_k(const unsigned short* __restrict__ xt,
                                                   const unsigned short* __restrict__ wpack,
                                                   const int* __restrict__ lists,
                                                   const float* __restrict__ bias,
                                                   float* __restrict__ out) {
  const int tid  = threadIdx.x;
  const int wave = tid >> 6;
  const int lane = tid & 63;
  const int wl   = lane & 15;     // MFMA row/col index
  const int kg   = lane >> 4;     // k-group (8 consecutive k per lane)

  const int h0 = blockIdx.x * TH;
  const int b  = blockIdx.y;
  const int ob = blockIdx.z;
  const int w0 = wave * 32;

  const int cnt = lists[ob];
  const bf16x8 bzero = {0, 0, 0, 0, 0, 0, 0, 0};

  for (int hh = 0; hh < TH; ++hh) {
    const int h = h0 + hh;
    f32x4 acc[2][2] = {};

    for (int s = 0; s < cnt; ++s) {
      const int ib = lists[4 + ob * 4 + s];
      const unsigned short* wp_base = wpack + (size_t)((ob * 4 + s) * 9) * 1024;
#pragma unroll
      for (int kh = 0; kh < 3; ++kh) {
        const int r = h + kh - 1;
        if (r < 0 || r >= H_) continue;      // uniform across WG
        const unsigned short* xrow = xt + (size_t)(b * H_ + r) * W_ * CIN_ + ib * 32 + kg * 8;
#pragma unroll
        for (int kw = 0; kw < 3; ++kw) {
          const unsigned short* wk = wp_base + (kh * 3 + kw) * 1024 + kg * 8;
          // A fragments: A[co][ci], lane: co = mi*16+wl, ci = kg*8..+7
          bf16x8 a0 = *(const bf16x8*)(wk + wl * 32);
          bf16x8 a1 = *(const bf16x8*)(wk + (wl + 16) * 32);
          // B fragments: B[ci][w], lane: w = w0+ni*16+wl+kw-1, ci = kg*8..+7
          const int wp1 = w0 + wl + kw - 1;
          const int wp2 = wp1 + 16;
          const int wc1 = wp1 < 0 ? 0 : (wp1 > W_ - 1 ? W_ - 1 : wp1);
          const int wc2 = wp2 < 0 ? 0 : (wp2 > W_ - 1 ? W_ - 1 : wp2);
          bf16x8 b0 = *(const bf16x8*)(xrow + (size_t)wc1 * CIN_);
          bf16x8 b1 = *(const bf16x8*)(xrow + (size_t)wc2 * CIN_);
          if (wp1 < 0 || wp1 > W_ - 1) b0 = bzero;
          if (wp2 < 0 || wp2 > W_ - 1) b1 = bzero;
          acc[0][0] = __builtin_amdgcn_mfma_f32_16x16x32_bf16(a0, b0, acc[0][0], 0, 0, 0);
          acc[0][1] = __builtin_amdgcn_mfma_f32_16x16x32_bf16(a0, b1, acc[0][1], 0, 0, 0);
          acc[1][0] = __builtin_amdgcn_mfma_f32_16x16x32_bf16(a1, b0, acc[1][0], 0, 0, 0);
          acc[1][1] = __builtin_amdgcn_mfma_f32_16x16x32_bf16(a1, b1, acc[1][1], 0, 0, 0);
        }
      }
    }

    // epilogue: C/D layout col = lane&15 (w), row = (lane>>4)*4 + j (co)
#pragma unroll
    for (int mi = 0; mi < 2; ++mi) {
#pragma unroll
      for (int j = 0; j < 4; ++j) {
        const int co = mi * 16 + kg * 4 + j;
        const float bv = bias[ob * 32 + co];
        float* yrow = out + ((size_t)(b * COUT_ + ob * 32 + co) * H_ + h) * W_;
        yrow[w0 + wl]      = acc[mi][0][j] + bv;
        yrow[w0 + wl + 16] = acc[mi][1][j] + bv;
      }
    }
  }
}

extern "C" void kernel_launch(void* const* d_in, const int* in_sizes, int n_in,
                              void* d_out, int out_size, void* d_ws, size_t ws_size,
                              hipStream_t stream) {
  const float* x      = (const float*)d_in[0];
  const float* weight = (const float*)d_in[1];
  const float* bias   = (const float*)d_in[2];
  const float* mask   = (const float*)d_in[3];
  float* out = (float*)d_out;

  // ws layout: [0,256)   : int lists (cnt[4], list[4][4])
  //            [256, +288K): packed bf16 weights
  //            [1MiB, +64MiB): transposed bf16 x  [b][h][w][ci]
  int* lists = (int*)d_ws;
  unsigned short* wpack = (unsigned short*)((char*)d_ws + 256);
  unsigned short* xt    = (unsigned short*)((char*)d_ws + (1u << 20));

  make_lists_k<<<1, 64, 0, stream>>>(mask, lists);
  pack_w_k<<<dim3(9, 4, 4), 256, 0, stream>>>(weight, mask, lists, wpack);
  transpose_cvt_k<<<dim3(2, 128, 16), 256, 0, stream>>>(x, xt);
  conv_mfma_k<<<dim3(H_ / TH, NBATCH, 4), 256, 0, stream>>>(xt, wpack, lists, bias, out);
}

// Round 2
// 123.161 us; speedup vs baseline: 1.3324x; 1.3324x over previous
//
#include <hip/hip_runtime.h>

#define NBATCH 16
#define CIN_ 128
#define COUT_ 128
#define H_ 128
#define W_ 128
#define WP_ 130   // padded width (w' = w+1, zeros at w'=0 and w'=129)
#define TH 4      // output rows per workgroup in conv kernel

typedef short bf16x8 __attribute__((ext_vector_type(8)));
typedef float f32x4 __attribute__((ext_vector_type(4)));
typedef unsigned short u16x8 __attribute__((ext_vector_type(8)));

__device__ __forceinline__ unsigned short f32_to_bf16(float f) {
  unsigned int u = __float_as_uint(f);
  u += 0x7fffu + ((u >> 16) & 1u);   // round-to-nearest-even
  return (unsigned short)(u >> 16);
}

// ---------------- kernel 1: decode block mask -> active lists ----------------
__global__ void make_lists_k(const float* __restrict__ mask, int* __restrict__ lists) {
  if (threadIdx.x == 0) {
    for (int i = 0; i < 20; ++i) lists[i] = 0;
    for (int ob = 0; ob < 4; ++ob) {
      int c = 0;
      for (int ib = 0; ib < 4; ++ib) {
        float v = mask[(size_t)((ob * 32) * CIN_ + ib * 32) * 9];
        if (v != 0.0f) { lists[4 + ob * 4 + c] = ib; ++c; }
      }
      lists[ob] = c;
    }
  }
}

// ---------------- kernel 2: pack masked weights to bf16, MFMA A-layout -------
// wpack[ob][slot][khkw][co(32)][ci(32)]  (ci contiguous)
__global__ __launch_bounds__(256) void pack_w_k(const float* __restrict__ weight,
                                                const float* __restrict__ mask,
                                                const int* __restrict__ lists,
                                                unsigned short* __restrict__ wpack) {
  const int khkw = blockIdx.x;   // 0..8
  const int slot = blockIdx.y;   // 0..3
  const int ob   = blockIdx.z;   // 0..3
  if (slot >= lists[ob]) return;
  const int ib = lists[4 + ob * 4 + slot];
  const int kh = khkw / 3, kw = khkw % 3;
  for (int e = threadIdx.x; e < 1024; e += 256) {
    const int co = e >> 5, ci = e & 31;
    const int cog = ob * 32 + co, cig = ib * 32 + ci;
    const size_t widx = ((size_t)(cog * CIN_ + cig) * 3 + kh) * 3 + kw;
    const float v = weight[widx] * mask[widx];
    wpack[(size_t)((ob * 4 + slot) * 9 + khkw) * 1024 + e] = f32_to_bf16(v);
  }
}

// ---------------- kernel 3a: zero the padding pixels of xt -------------------
__global__ __launch_bounds__(256) void pad_k(unsigned short* __restrict__ xt) {
  const int b = blockIdx.x, h = blockIdx.y;
  const int t = threadIdx.x;            // 0..255
  const int wp = (t >> 7) ? (WP_ - 1) : 0;
  const int ci = t & 127;
  xt[((size_t)(b * H_ + h) * WP_ + wp) * CIN_ + ci] = 0;
}

// ---------------- kernel 3b: transpose+convert x: NCHW f32 -> [b][h][w+1][ci] bf16
__global__ __launch_bounds__(256) void transpose_cvt_k(const float* __restrict__ x,
                                                       unsigned short* __restrict__ xt) {
  __shared__ float lds[128 * 65];     // [ci][w], pitch 65 to break bank conflicts
  const int tid = threadIdx.x;
  const int w0 = blockIdx.x * 64;     // 0 or 64
  const int h  = blockIdx.y;
  const int b  = blockIdx.z;

  // load: coalesced rows of x (w contiguous)
  {
    const int wl = tid & 63;
    const int c0 = tid >> 6;          // 0..3
    for (int ci = c0; ci < 128; ci += 4) {
      lds[ci * 65 + wl] = x[((size_t)(b * CIN_ + ci) * H_ + h) * W_ + w0 + wl];
    }
  }
  __syncthreads();

  // store: each thread emits one 16B chunk (8 ci) per rep; coalesced
  {
    const int chunk = tid & 15;       // which 8-ci chunk of the pixel
    const int wloc  = tid >> 4;       // 0..15
    for (int rep = 0; rep < 4; ++rep) {
      const int w = wloc + rep * 16;  // 0..63
      u16x8 v;
#pragma unroll
      for (int j = 0; j < 8; ++j) {
        v[j] = f32_to_bf16(lds[(chunk * 8 + j) * 65 + w]);
      }
      *(u16x8*)(xt + ((size_t)(b * H_ + h) * WP_ + (w0 + w + 1)) * CIN_ + chunk * 8) = v;
    }
  }
}

// ---------------- kernel 4: block-sparse implicit-GEMM conv via MFMA ---------
// grid: (H/TH, B, 4 output blocks), block 256 (4 waves over w)
// Input-row-major loop: each staged row's B frags feed all 3 kh targets.
__global__ __launch_bounds__(256, 2) void conv_mfma_k(const unsigned short* __restrict__ xt,
                                                      const unsigned short* __restrict__ wpack,
                                                      const int* __restrict__ lists,
                                                      const float* __restrict__ bias,
                                                      float* __restrict__ out) {
  const int tid  = threadIdx.x;
  const int wave = tid >> 6;
  const int lane = tid & 63;
  const int wl   = lane & 15;     // MFMA row/col index
  const int kg   = lane >> 4;     // k-group (8 consecutive k per lane)

  const int h0 = blockIdx.x * TH;
  const int b  = blockIdx.y;
  const int ob = blockIdx.z;
  const int w0 = wave * 32;

  const int cnt = lists[ob];

  f32x4 acc[TH][2][2] = {};

  // lane-fixed base into padded xt: + r*WP_*CIN_ + ib*32 + (ni*16+kw)*CIN_
  // padded w index for (ni, kw): w' = w0 + ni*16 + wl + kw   (w = w'-1)
  const unsigned short* xbase =
      xt + (size_t)b * H_ * WP_ * CIN_ + (size_t)(w0 + wl) * CIN_ + kg * 8;

  for (int s = 0; s < cnt; ++s) {
    const int ib = lists[4 + ob * 4 + s];

    // hoist all 18 A fragments for this input block (reused across TH rows)
    const unsigned short* wk =
        wpack + (size_t)((ob * 4 + s) * 9) * 1024 + wl * 32 + kg * 8;
    bf16x8 a[3][3][2];
#pragma unroll
    for (int kh = 0; kh < 3; ++kh)
#pragma unroll
      for (int kw = 0; kw < 3; ++kw) {
        a[kh][kw][0] = *(const bf16x8*)(wk + (kh * 3 + kw) * 1024);
        a[kh][kw][1] = *(const bf16x8*)(wk + (kh * 3 + kw) * 1024 + 16 * 32);
      }

    const unsigned short* xb = xbase + ib * 32;

#pragma unroll
    for (int ridx = 0; ridx < TH + 2; ++ridx) {
      const int r = h0 - 1 + ridx;          // input row
      if (r < 0 || r >= H_) continue;       // WG-uniform guard
      const unsigned short* xr = xb + (size_t)r * WP_ * CIN_;

      bf16x8 bf[2][3];
#pragma unroll
      for (int ni = 0; ni < 2; ++ni)
#pragma unroll
        for (int kw = 0; kw < 3; ++kw)
          bf[ni][kw] = *(const bf16x8*)(xr + (ni * 16 + kw) * CIN_);

#pragma unroll
      for (int kh = 0; kh < 3; ++kh) {
        const int hi = ridx - kh;           // output row h0+hi uses input r with tap kh
        if (hi < 0 || hi >= TH) continue;   // compile-time prune
#pragma unroll
        for (int kw = 0; kw < 3; ++kw) {
          acc[hi][0][0] = __builtin_amdgcn_mfma_f32_16x16x32_bf16(a[kh][kw][0], bf[0][kw], acc[hi][0][0], 0, 0, 0);
          acc[hi][0][1] = __builtin_amdgcn_mfma_f32_16x16x32_bf16(a[kh][kw][0], bf[1][kw], acc[hi][0][1], 0, 0, 0);
          acc[hi][1][0] = __builtin_amdgcn_mfma_f32_16x16x32_bf16(a[kh][kw][1], bf[0][kw], acc[hi][1][0], 0, 0, 0);
          acc[hi][1][1] = __builtin_amdgcn_mfma_f32_16x16x32_bf16(a[kh][kw][1], bf[1][kw], acc[hi][1][1], 0, 0, 0);
        }
      }
    }
  }

  // epilogue: C/D layout col = lane&15 (w), row = (lane>>4)*4 + j (co)  [HW-verified r1]
#pragma unroll
  for (int mi = 0; mi < 2; ++mi)
#pragma unroll
    for (int j = 0; j < 4; ++j) {
      const int co = mi * 16 + kg * 4 + j;
      const float bv = bias[ob * 32 + co];
#pragma unroll
      for (int hh = 0; hh < TH; ++hh) {
        float* yrow = out + ((size_t)(b * COUT_ + ob * 32 + co) * H_ + h0 + hh) * W_;
        yrow[w0 + wl]      = acc[hh][mi][0][j] + bv;
        yrow[w0 + wl + 16] = acc[hh][mi][1][j] + bv;
      }
    }
}

extern "C" void kernel_launch(void* const* d_in, const int* in_sizes, int n_in,
                              void* d_out, int out_size, void* d_ws, size_t ws_size,
                              hipStream_t stream) {
  const float* x      = (const float*)d_in[0];
  const float* weight = (const float*)d_in[1];
  const float* bias   = (const float*)d_in[2];
  const float* mask   = (const float*)d_in[3];
  float* out = (float*)d_out;

  // ws layout: [0, 4K)      : int lists (cnt[4], list[4][4])
  //            [4K, +288K)  : packed bf16 weights
  //            [512K, +65M) : transposed bf16 x  [b][h][w'(130)][ci]
  int* lists = (int*)d_ws;
  unsigned short* wpack = (unsigned short*)((char*)d_ws + 4096);
  unsigned short* xt    = (unsigned short*)((char*)d_ws + (512u << 10));

  make_lists_k<<<1, 64, 0, stream>>>(mask, lists);
  pack_w_k<<<dim3(9, 4, 4), 256, 0, stream>>>(weight, mask, lists, wpack);
  pad_k<<<dim3(NBATCH, H_), 256, 0, stream>>>(xt);
  transpose_cvt_k<<<dim3(2, H_, NBATCH), 256, 0, stream>>>(x, xt);
  conv_mfma_k<<<dim3(H_ / TH, NBATCH, 4), 256, 0, stream>>>(xt, wpack, lists, bias, out);
}

// Round 3
// 101.869 us; speedup vs baseline: 1.6109x; 1.2090x over previous
//
#include <hip/hip_runtime.h>

#define NBATCH 16
#define CIN_ 128
#define COUT_ 128
#define H_ 128
#define W_ 128
#define TH 4      // output rows per workgroup
#define NR (TH + 2)        // staged input rows
#define CPITCH 34          // ci pitch in LDS tile (odd word stride -> no bank conflicts)

typedef short bf16x8 __attribute__((ext_vector_type(8)));
typedef float f32x4 __attribute__((ext_vector_type(4)));

__device__ __forceinline__ unsigned short f32_to_bf16(float f) {
  unsigned int u = __float_as_uint(f);
  u += 0x7fffu + ((u >> 16) & 1u);   // round-to-nearest-even
  return (unsigned short)(u >> 16);
}

// ---------------- kernel 1: decode block mask -> active lists ----------------
__global__ void make_lists_k(const float* __restrict__ mask, int* __restrict__ lists) {
  if (threadIdx.x == 0) {
    for (int i = 0; i < 20; ++i) lists[i] = 0;
    for (int ob = 0; ob < 4; ++ob) {
      int c = 0;
      for (int ib = 0; ib < 4; ++ib) {
        float v = mask[(size_t)((ob * 32) * CIN_ + ib * 32) * 9];
        if (v != 0.0f) { lists[4 + ob * 4 + c] = ib; ++c; }
      }
      lists[ob] = c;
    }
  }
}

// ---------------- kernel 2: pack masked weights to bf16, MFMA A-layout -------
// wpack[ob][slot][khkw][co(32)][ci(32)]  (ci contiguous)
__global__ __launch_bounds__(256) void pack_w_k(const float* __restrict__ weight,
                                                const float* __restrict__ mask,
                                                const int* __restrict__ lists,
                                                unsigned short* __restrict__ wpack) {
  const int khkw = blockIdx.x;   // 0..8
  const int slot = blockIdx.y;   // 0..3
  const int ob   = blockIdx.z;   // 0..3
  if (slot >= lists[ob]) return;
  const int ib = lists[4 + ob * 4 + slot];
  const int kh = khkw / 3, kw = khkw % 3;
  for (int e = threadIdx.x; e < 1024; e += 256) {
    const int co = e >> 5, ci = e & 31;
    const int cog = ob * 32 + co, cig = ib * 32 + ci;
    const size_t widx = ((size_t)(cog * CIN_ + cig) * 3 + kh) * 3 + kw;
    const float v = weight[widx] * mask[widx];
    wpack[(size_t)((ob * 4 + slot) * 9 + khkw) * 1024 + e] = f32_to_bf16(v);
  }
}

// ---------------- kernel 3: fused transpose+conv (block-sparse implicit GEMM)
// grid: (H/TH, B, 4 output blocks), block 256 (4 waves over w)
// Per s (active input block): stage [NR rows][130 w'][32 ci] bf16 tile in LDS
// straight from NCHW fp32 x, then MFMA with input-row-major accumulation.
__global__ __launch_bounds__(256, 2) void conv_fused_k(const float* __restrict__ x,
                                                       const unsigned short* __restrict__ wpack,
                                                       const int* __restrict__ lists,
                                                       const float* __restrict__ bias,
                                                       float* __restrict__ out) {
  __shared__ unsigned short xs[NR * 130 * CPITCH];   // 53 KB

  const int tid  = threadIdx.x;
  const int wave = tid >> 6;
  const int lane = tid & 63;
  const int wl   = lane & 15;     // MFMA row/col index
  const int kg   = lane >> 4;     // k-group (8 consecutive k per lane)

  const int h0 = blockIdx.x * TH;
  const int b  = blockIdx.y;
  const int ob = blockIdx.z;
  const int w0 = wave * 32;

  const int cnt = lists[ob];

  f32x4 acc[TH][2][2] = {};

  const int wloc  = tid & 127;    // staging: w column
  const int chalf = tid >> 7;     // staging: ci parity

  for (int s = 0; s < cnt; ++s) {
    const int ib = lists[4 + ob * 4 + s];

    __syncthreads();   // previous compute done reading xs

    // ---- stage x[b][ib*32..+31][h0-1..h0+TH][*] -> xs (bf16, transposed) ----
    {
      const float* xrow0 = x + ((size_t)b * CIN_ + ib * 32) * H_ * W_ + wloc;
#pragma unroll
      for (int r = 0; r < NR; ++r) {
        const int row = h0 - 1 + r;
        const bool rv = (row >= 0) && (row < H_);
        const float* xr = xrow0 + (size_t)(rv ? row : 0) * W_;
        unsigned short* xd = xs + (r * 130 + wloc + 1) * CPITCH + chalf;
#pragma unroll
        for (int cc = 0; cc < 16; ++cc) {
          const int ci = cc * 2 + chalf;
          float v = rv ? xr[(size_t)ci * (H_ * W_)] : 0.0f;
          xd[cc * 2] = f32_to_bf16(v);
        }
      }
      // zero the w' = 0 and w' = 129 padding columns
      for (int e = tid; e < NR * 2 * 32; e += 256) {
        const int r = e >> 6, edge = (e >> 5) & 1, ci = e & 31;
        xs[(r * 130 + (edge ? 129 : 0)) * CPITCH + ci] = 0;
      }
    }

    // ---- hoist all 18 A fragments for this input block ----
    const unsigned short* wk =
        wpack + (size_t)((ob * 4 + s) * 9) * 1024 + wl * 32 + kg * 8;
    bf16x8 a[3][3][2];
#pragma unroll
    for (int kh = 0; kh < 3; ++kh)
#pragma unroll
      for (int kw = 0; kw < 3; ++kw) {
        a[kh][kw][0] = *(const bf16x8*)(wk + (kh * 3 + kw) * 1024);
        a[kh][kw][1] = *(const bf16x8*)(wk + (kh * 3 + kw) * 1024 + 16 * 32);
      }

    __syncthreads();   // tile staged

    // ---- compute: input-row-major, B frags from LDS ----
#pragma unroll
    for (int ridx = 0; ridx < NR; ++ridx) {
      bf16x8 bf[2][3];
#pragma unroll
      for (int ni = 0; ni < 2; ++ni)
#pragma unroll
        for (int kw = 0; kw < 3; ++kw)
          bf[ni][kw] = *(const bf16x8*)(xs + (ridx * 130 + w0 + ni * 16 + wl + kw) * CPITCH + kg * 8);

#pragma unroll
      for (int kh = 0; kh < 3; ++kh) {
        const int hi = ridx - kh;           // output row h0+hi uses input r with tap kh
        if (hi < 0 || hi >= TH) continue;   // compile-time prune
#pragma unroll
        for (int kw = 0; kw < 3; ++kw) {
          acc[hi][0][0] = __builtin_amdgcn_mfma_f32_16x16x32_bf16(a[kh][kw][0], bf[0][kw], acc[hi][0][0], 0, 0, 0);
          acc[hi][0][1] = __builtin_amdgcn_mfma_f32_16x16x32_bf16(a[kh][kw][0], bf[1][kw], acc[hi][0][1], 0, 0, 0);
          acc[hi][1][0] = __builtin_amdgcn_mfma_f32_16x16x32_bf16(a[kh][kw][1], bf[0][kw], acc[hi][1][0], 0, 0, 0);
          acc[hi][1][1] = __builtin_amdgcn_mfma_f32_16x16x32_bf16(a[kh][kw][1], bf[1][kw], acc[hi][1][1], 0, 0, 0);
        }
      }
    }
  }

  // epilogue: C/D layout col = lane&15 (w), row = (lane>>4)*4 + j (co)  [HW-verified r1]
#pragma unroll
  for (int mi = 0; mi < 2; ++mi)
#pragma unroll
    for (int j = 0; j < 4; ++j) {
      const int co = mi * 16 + kg * 4 + j;
      const float bv = bias[ob * 32 + co];
#pragma unroll
      for (int hh = 0; hh < TH; ++hh) {
        float* yrow = out + ((size_t)(b * COUT_ + ob * 32 + co) * H_ + h0 + hh) * W_;
        yrow[w0 + wl]      = acc[hh][mi][0][j] + bv;
        yrow[w0 + wl + 16] = acc[hh][mi][1][j] + bv;
      }
    }
}

extern "C" void kernel_launch(void* const* d_in, const int* in_sizes, int n_in,
                              void* d_out, int out_size, void* d_ws, size_t ws_size,
                              hipStream_t stream) {
  const float* x      = (const float*)d_in[0];
  const float* weight = (const float*)d_in[1];
  const float* bias   = (const float*)d_in[2];
  const float* mask   = (const float*)d_in[3];
  float* out = (float*)d_out;

  // ws layout: [0, 4K) : int lists ; [4K, +288K) : packed bf16 weights
  int* lists = (int*)d_ws;
  unsigned short* wpack = (unsigned short*)((char*)d_ws + 4096);

  make_lists_k<<<1, 64, 0, stream>>>(mask, lists);
  pack_w_k<<<dim3(9, 4, 4), 256, 0, stream>>>(weight, mask, lists, wpack);
  conv_fused_k<<<dim3(H_ / TH, NBATCH, 4), 256, 0, stream>>>(x, wpack, lists, bias, out);
}

// Round 4
// 74.488 us; speedup vs baseline: 2.2030x; 1.3676x over previous
//
#include <hip/hip_runtime.h>

#define NBATCH 16
#define CIN_ 128
#define COUT_ 128
#define H_ 128
#define W_ 128
#define TH 4               // output rows per workgroup
#define NR (TH + 2)        // staged input rows
#define CPITCH 34          // ci pitch in LDS tile (odd word stride -> conflict-light reads)

typedef short bf16x8 __attribute__((ext_vector_type(8)));
typedef float f32x4 __attribute__((ext_vector_type(4)));

__device__ __forceinline__ unsigned short f32_to_bf16(float f) {
  unsigned int u = __float_as_uint(f);
  u += 0x7fffu + ((u >> 16) & 1u);   // round-to-nearest-even
  return (unsigned short)(u >> 16);
}

// ---------------- kernel 1: decode block mask -> active lists ----------------
__global__ void make_lists_k(const float* __restrict__ mask, int* __restrict__ lists) {
  if (threadIdx.x == 0) {
    for (int i = 0; i < 20; ++i) lists[i] = 0;
    for (int ob = 0; ob < 4; ++ob) {
      int c = 0;
      for (int ib = 0; ib < 4; ++ib) {
        float v = mask[(size_t)((ob * 32) * CIN_ + ib * 32) * 9];
        if (v != 0.0f) { lists[4 + ob * 4 + c] = ib; ++c; }
      }
      lists[ob] = c;
    }
  }
}

// ---------------- kernel 2: pack masked weights to bf16, MFMA A-layout -------
// wpack[ob][slot][khkw][co(32)][ci(32)]  (ci contiguous)
__global__ __launch_bounds__(256) void pack_w_k(const float* __restrict__ weight,
                                                const float* __restrict__ mask,
                                                const int* __restrict__ lists,
                                                unsigned short* __restrict__ wpack) {
  const int khkw = blockIdx.x;   // 0..8
  const int slot = blockIdx.y;   // 0..3
  const int ob   = blockIdx.z;   // 0..3
  if (slot >= lists[ob]) return;
  const int ib = lists[4 + ob * 4 + slot];
  const int kh = khkw / 3, kw = khkw % 3;
  for (int e = threadIdx.x; e < 1024; e += 256) {
    const int co = e >> 5, ci = e & 31;
    const int cog = ob * 32 + co, cig = ib * 32 + ci;
    const size_t widx = ((size_t)(cog * CIN_ + cig) * 3 + kh) * 3 + kw;
    const float v = weight[widx] * mask[widx];
    wpack[(size_t)((ob * 4 + slot) * 9 + khkw) * 1024 + e] = f32_to_bf16(v);
  }
}

// ---------------- kernel 3: fused transpose+conv (block-sparse implicit GEMM)
// grid: (H/TH, B, 4 output blocks), block 256 (4 waves over w)
__global__ __launch_bounds__(256, 3) void conv_fused_k(const float* __restrict__ x,
                                                       const unsigned short* __restrict__ wpack,
                                                       const int* __restrict__ lists,
                                                       const float* __restrict__ bias,
                                                       float* __restrict__ out) {
  __shared__ unsigned short xs[NR * 130 * CPITCH];   // 53 KB

  const int tid  = threadIdx.x;
  const int wave = tid >> 6;
  const int lane = tid & 63;
  const int wl   = lane & 15;     // MFMA row/col index
  const int kg   = lane >> 4;     // k-group (8 consecutive k per lane)

  const int h0 = blockIdx.x * TH;
  const int b  = blockIdx.y;
  const int ob = blockIdx.z;
  const int w0 = wave * 32;

  const int cnt = lists[ob];

  f32x4 acc[TH][2][2] = {};

  // staging decomposition: quad q = w/4, group g picks (row, ci-pair)
  const int q = tid & 31;         // w quad: w = q*4 + j
  const int g = tid >> 5;         // 0..7

  for (int s = 0; s < cnt; ++s) {
    const int ib = lists[4 + ob * 4 + s];

    if (s) __syncthreads();   // previous compute done reading xs

    // ---- stage x[b][ib*32..+31][h0-1..h0+TH][*] -> xs (bf16, transposed) ----
    {
      const float* xbase = x + ((size_t)b * CIN_ + ib * 32) * H_ * W_ + q * 4;
#pragma unroll
      for (int it = 0; it < 12; ++it) {
        const int combo = it * 8 + g;       // 0..95
        const int r  = combo >> 4;          // 0..5
        const int cp = combo & 15;          // ci pair index
        const int row = h0 - 1 + r;
        const bool rv = (row >= 0) && (row < H_);
        const float* src = xbase + ((size_t)(cp * 2) * H_ + (rv ? row : 0)) * W_;
        f32x4 va = *(const f32x4*)src;
        f32x4 vb = *(const f32x4*)(src + (size_t)H_ * W_);
        unsigned int* xd = (unsigned int*)(xs + (r * 130 + q * 4 + 1) * CPITCH + cp * 2);
#pragma unroll
        for (int j = 0; j < 4; ++j) {
          unsigned int lo = rv ? (unsigned int)f32_to_bf16(va[j]) : 0u;
          unsigned int hi = rv ? (unsigned int)f32_to_bf16(vb[j]) : 0u;
          xd[j * (CPITCH / 2)] = lo | (hi << 16);
        }
      }
      // zero the w' = 0 and w' = 129 padding columns (NR*2*32 = 384 elems)
      for (int e = tid; e < NR * 2 * 32; e += 256) {
        const int r = e >> 6, edge = (e >> 5) & 1, ci = e & 31;
        xs[(r * 130 + (edge ? 129 : 0)) * CPITCH + ci] = 0;
      }
    }

    // ---- hoist all 18 A fragments for this input block (global, independent) ----
    const unsigned short* wk =
        wpack + (size_t)((ob * 4 + s) * 9) * 1024 + wl * 32 + kg * 8;
    bf16x8 a[3][3][2];
#pragma unroll
    for (int kh = 0; kh < 3; ++kh)
#pragma unroll
      for (int kw = 0; kw < 3; ++kw) {
        a[kh][kw][0] = *(const bf16x8*)(wk + (kh * 3 + kw) * 1024);
        a[kh][kw][1] = *(const bf16x8*)(wk + (kh * 3 + kw) * 1024 + 16 * 32);
      }

    __syncthreads();   // tile staged

    // ---- compute: input-row-major, B frags from LDS ----
#pragma unroll
    for (int ridx = 0; ridx < NR; ++ridx) {
      bf16x8 bf[2][3];
#pragma unroll
      for (int ni = 0; ni < 2; ++ni)
#pragma unroll
        for (int kw = 0; kw < 3; ++kw)
          bf[ni][kw] = *(const bf16x8*)(xs + (ridx * 130 + w0 + ni * 16 + wl + kw) * CPITCH + kg * 8);

#pragma unroll
      for (int kh = 0; kh < 3; ++kh) {
        const int hi = ridx - kh;           // output row h0+hi uses input r with tap kh
        if (hi < 0 || hi >= TH) continue;   // compile-time prune
#pragma unroll
        for (int kw = 0; kw < 3; ++kw) {
          acc[hi][0][0] = __builtin_amdgcn_mfma_f32_16x16x32_bf16(a[kh][kw][0], bf[0][kw], acc[hi][0][0], 0, 0, 0);
          acc[hi][0][1] = __builtin_amdgcn_mfma_f32_16x16x32_bf16(a[kh][kw][0], bf[1][kw], acc[hi][0][1], 0, 0, 0);
          acc[hi][1][0] = __builtin_amdgcn_mfma_f32_16x16x32_bf16(a[kh][kw][1], bf[0][kw], acc[hi][1][0], 0, 0, 0);
          acc[hi][1][1] = __builtin_amdgcn_mfma_f32_16x16x32_bf16(a[kh][kw][1], bf[1][kw], acc[hi][1][1], 0, 0, 0);
        }
      }
    }
  }

  // epilogue: C/D layout col = lane&15 (w), row = (lane>>4)*4 + j (co)  [HW-verified r1]
#pragma unroll
  for (int mi = 0; mi < 2; ++mi)
#pragma unroll
    for (int j = 0; j < 4; ++j) {
      const int co = mi * 16 + kg * 4 + j;
      const float bv = bias[ob * 32 + co];
#pragma unroll
      for (int hh = 0; hh < TH; ++hh) {
        float* yrow = out + ((size_t)(b * COUT_ + ob * 32 + co) * H_ + h0 + hh) * W_;
        yrow[w0 + wl]      = acc[hh][mi][0][j] + bv;
        yrow[w0 + wl + 16] = acc[hh][mi][1][j] + bv;
      }
    }
}

extern "C" void kernel_launch(void* const* d_in, const int* in_sizes, int n_in,
                              void* d_out, int out_size, void* d_ws, size_t ws_size,
                              hipStream_t stream) {
  const float* x      = (const float*)d_in[0];
  const float* weight = (const float*)d_in[1];
  const float* bias   = (const float*)d_in[2];
  const float* mask   = (const float*)d_in[3];
  float* out = (float*)d_out;

  // ws layout: [0, 4K) : int lists ; [4K, +288K) : packed bf16 weights
  int* lists = (int*)d_ws;
  unsigned short* wpack = (unsigned short*)((char*)d_ws + 4096);

  make_lists_k<<<1, 64, 0, stream>>>(mask, lists);
  pack_w_k<<<dim3(9, 4, 4), 256, 0, stream>>>(weight, mask, lists, wpack);
  conv_fused_k<<<dim3(H_ / TH, NBATCH, 4), 256, 0, stream>>>(x, wpack, lists, bias, out);
}